// Round 6
// baseline (239.713 us; speedup 1.0000x reference)
//
#include <hip/hip_runtime.h>
#include <math.h>

// Router: logits = x @ w^T (N=32768, C=1024, E=64), top-2 + softmax, stable
// k-major position-in-expert, capacity mask.
//
// K2 router_main (this round's change): 32 tokens/block, 8 waves =
//   (K-quarter 0..3) x (expert-half 0..1). ALL w-fragments preloaded to
//   registers (no vmem in K-loop except x-DMA). x streamed via
//   global_load_lds (1 instr = 1 contiguous row of 1KB) into a double-
//   buffered padded LDS tile. Loop barriers are raw s_barrier with explicit
//   s_waitcnt vmcnt(4) so next-chunk DMAs stay in flight across the barrier
//   (never drain to 0 in steady state).

#define C_DIM 1024

typedef _Float16 f16x8 __attribute__((ext_vector_type(8)));
typedef float f32x16 __attribute__((ext_vector_type(16)));

#define ASYNC_BAR4() asm volatile("s_waitcnt vmcnt(4)\ns_barrier" ::: "memory")
#define ASYNC_BAR0() asm volatile("s_waitcnt vmcnt(0)\ns_barrier" ::: "memory")
#define RAW_BAR()    asm volatile("s_barrier" ::: "memory")

// wf frag id q = s*4 + eh*2 + split; elem = q*512 + lane*8
// content: n = eh*32 + (lane&31) (expert), k = s*16 + (lane>>5)*8 + j
__global__ __launch_bounds__(256) void wprep(const float* __restrict__ w,
                                             _Float16* __restrict__ wf,
                                             int* __restrict__ hist, int histN) {
    int id = blockIdx.x * 256 + threadIdx.x;   // 16384
    if (id * 4 < histN)
        *(int4*)(hist + id * 4) = make_int4(0, 0, 0, 0);
    int lane = id & 63;
    int q = id >> 6;            // 0..255
    int split = q & 1;
    int eh = (q >> 1) & 1;
    int s = q >> 2;             // 0..63
    int n = eh * 32 + (lane & 31);
    int k = s * 16 + (lane >> 5) * 8;
    const float* src = w + (size_t)n * C_DIM + k;
    f16x8 v;
    #pragma unroll
    for (int j = 0; j < 8; ++j) {
        float xv = src[j];
        _Float16 h = (_Float16)xv;
        v[j] = (split == 0) ? h : (_Float16)((xv - (float)h) * 2048.0f);
    }
    *(f16x8*)(wf + (size_t)id * 8) = v;
}

#define ROWSTRIDE 260   // 256 floats + 16B pad (per-row DMA allows padding)

__global__ __launch_bounds__(512, 2) void router_main(
    const float* __restrict__ x, const _Float16* __restrict__ wf,
    int2* __restrict__ idx_ws, float2* __restrict__ probs_ws,
    int* __restrict__ hist)
{
    __shared__ __align__(16) float xs[2 * 32 * ROWSTRIDE];   // ~65 KB dbuf
    __shared__ int h2[128];

    const int tid  = threadIdx.x;
    const int lane = tid & 63;
    const int wv   = __builtin_amdgcn_readfirstlane(tid >> 6); // 0..7
    const int kq   = wv >> 1;      // K-quarter within chunk
    const int eh   = wv & 1;       // expert half
    const int braw = blockIdx.x;
    const int b    = ((braw & 7) << 7) | (braw >> 3);   // XCD swizzle (grid 1024)
    const int m0   = b * 32;
    const int lh   = lane >> 5;
    const int mm   = lane & 31;

    // ---- preload all w-fragments for this wave's (kq, eh) into registers ----
    f16x8 wh[16], wm[16];
    #pragma unroll
    for (int ch = 0; ch < 4; ++ch)
        #pragma unroll
        for (int j = 0; j < 4; ++j) {
            int s = ch * 16 + kq * 4 + j;
            const _Float16* base = wf + (size_t)(s * 4 + eh * 2) * 512 + lane * 8;
            wh[ch * 4 + j] = *(const f16x8*)(base);
            wm[ch * 4 + j] = *(const f16x8*)(base + 512);
        }

    // per-lane global base pointers: wave wv owns rows wv*4..wv*4+3;
    // one DMA instr = one contiguous 1KB row chunk (lane*16B within it)
    const float* gp[4];
    #pragma unroll
    for (int i = 0; i < 4; ++i)
        gp[i] = x + (size_t)(m0 + wv * 4 + i) * C_DIM + lane * 4;

    f32x16 ah, am;
    #pragma unroll
    for (int i = 0; i < 16; ++i) { ah[i] = 0.f; am[i] = 0.f; }

    // prologue: chunk 0 -> buf 0
    #pragma unroll
    for (int i = 0; i < 4; ++i)
        __builtin_amdgcn_global_load_lds(
            (const __attribute__((address_space(1))) uint32_t*)(gp[i]),
            (__attribute__((address_space(3))) uint32_t*)(xs + (size_t)(wv * 4 + i) * ROWSTRIDE),
            16, 0, 0);

    #pragma unroll
    for (int ch = 0; ch < 4; ++ch) {
        const int cur = ch & 1;
        const int nxt = cur ^ 1;
        if (ch < 3) {
            #pragma unroll
            for (int i = 0; i < 4; ++i)
                __builtin_amdgcn_global_load_lds(
                    (const __attribute__((address_space(1))) uint32_t*)(gp[i] + (ch + 1) * 256),
                    (__attribute__((address_space(3))) uint32_t*)(xs + (size_t)(nxt * 32 + wv * 4 + i) * ROWSTRIDE),
                    16, 0, 0);
            ASYNC_BAR4();   // wait cur's 4 DMAs; nxt's 4 stay in flight
        } else {
            ASYNC_BAR0();
        }
        const float* xb = xs + (size_t)cur * 32 * ROWSTRIDE + (size_t)mm * ROWSTRIDE + lh * 8;
        #pragma unroll
        for (int j = 0; j < 4; ++j) {
            const int k0 = (kq * 4 + j) * 16;
            float4 a0 = *(const float4*)(xb + k0);
            float4 a1 = *(const float4*)(xb + k0 + 4);
            float av[8] = {a0.x, a0.y, a0.z, a0.w, a1.x, a1.y, a1.z, a1.w};
            f16x8 xh, xm;
            #pragma unroll
            for (int q = 0; q < 8; ++q) {
                _Float16 hh = (_Float16)av[q];
                xh[q] = hh;
                xm[q] = (_Float16)((av[q] - (float)hh) * 2048.0f);
            }
            const int wi = ch * 4 + j;
            ah = __builtin_amdgcn_mfma_f32_32x32x16_f16(xh, wh[wi], ah, 0, 0, 0);
            am = __builtin_amdgcn_mfma_f32_32x32x16_f16(xh, wm[wi], am, 0, 0, 0);
            am = __builtin_amdgcn_mfma_f32_32x32x16_f16(xm, wh[wi], am, 0, 0, 0);
        }
        RAW_BAR();   // all waves done reading buf[cur]; next iter reuses it
    }

    // ---- epilogue: reduce over kq into part (aliases xs), top-2, histogram ----
    float* part = xs;   // 32 x 68 floats
    if (tid < 128) h2[tid] = 0;
    const float inv = 1.0f / 2048.0f;
    #pragma unroll 1
    for (int r = 0; r < 4; ++r) {
        if (kq == r) {
            #pragma unroll
            for (int reg = 0; reg < 16; ++reg) {
                int row = (reg & 3) + 8 * (reg >> 2) + 4 * lh;
                float v = ah[reg] + am[reg] * inv;
                if (r == 0) part[row * 68 + eh * 32 + mm] = v;
                else        part[row * 68 + eh * 32 + mm] += v;
            }
        }
        __syncthreads();   // no DMA outstanding here; full sync fine
    }

    if (tid < 32) {
        float m1 = -3.0e38f, m2 = -3.0e38f;
        int   i1 = 0, i2 = 0;
        const float* row = part + tid * 68;
        for (int e = 0; e < 64; ++e) {
            float v = row[e];
            if (v > m1)      { m2 = m1; i2 = i1; m1 = v; i1 = e; }
            else if (v > m2) { m2 = v;  i2 = e; }
        }
        float e2 = expf(m2 - m1);
        float p1 = 1.f / (1.f + e2);
        int n = m0 + tid;
        probs_ws[n] = make_float2(p1, e2 * p1);
        idx_ws[n]   = make_int2(i1, i2);
        atomicAdd(&h2[i1], 1);
        atomicAdd(&h2[64 + i2], 1);
    }
    __syncthreads();
    if (tid < 128) {
        int v = h2[tid];
        if (v) atomicAdd(&hist[(size_t)(m0 >> 6) * 128 + tid], v);
    }
}

// exclusive prefix over groups for each of the 128 (k,expert) columns
__global__ __launch_bounds__(256) void scan_kernel(const int* __restrict__ hist,
                                                   int* __restrict__ offs,
                                                   int* __restrict__ tot, int G) {
    int c = blockIdx.x;          // 0..127
    int t = threadIdx.x;
    int ipt = G / 256;
    int base = t * ipt;
    int sum = 0;
    for (int j = 0; j < ipt; ++j) sum += hist[(size_t)(base + j) * 128 + c];
    int lane = t & 63, wvi = t >> 6;
    int sc = sum;
    #pragma unroll
    for (int d = 1; d < 64; d <<= 1) {
        int o = __shfl_up(sc, d, 64);
        if (lane >= d) sc += o;
    }
    __shared__ int wtot[4];
    if (lane == 63) wtot[wvi] = sc;
    __syncthreads();
    int pre = 0;
    for (int w2 = 0; w2 < wvi; ++w2) pre += wtot[w2];
    int run = pre + sc - sum;
    for (int j = 0; j < ipt; ++j) {
        int v = hist[(size_t)(base + j) * 128 + c];
        offs[(size_t)(base + j) * 128 + c] = run;
        run += v;
    }
    if (t == 255) tot[c] = run;
}

__global__ __launch_bounds__(256) void rank_out(
    const int2* __restrict__ idx_ws, const float2* __restrict__ probs_ws,
    const int* __restrict__ offs, const int* __restrict__ tot,
    float* __restrict__ out_mask, float* __restrict__ out_probs,
    float* __restrict__ out_idx,  float* __restrict__ out_rank, int cap)
{
    __shared__ float msk[64 * 128];   // 32 KB
    const int g = blockIdx.x, t = threadIdx.x;

    #pragma unroll
    for (int j = 0; j < 8; ++j)
        *(float4*)&msk[(size_t)(j * 256 + t) * 4] = make_float4(0.f, 0.f, 0.f, 0.f);
    __syncthreads();

    if (t < 64) {
        const int l = t;
        const int n = g * 64 + l;
        int2   ii = idx_ws[n];
        float2 pp = probs_ws[n];
        int off0 = offs[g * 128 + ii.x];
        int off1 = offs[g * 128 + 64 + ii.y] + tot[ii.y];

        unsigned long long below = (1ull << l) - 1ull;
        unsigned long long mk0 = ~0ull, mk1 = ~0ull;
        #pragma unroll
        for (int bi = 0; bi < 6; ++bi) {
            unsigned long long b0 = __ballot((ii.x >> bi) & 1);
            unsigned long long b1 = __ballot((ii.y >> bi) & 1);
            mk0 &= ((ii.x >> bi) & 1) ? b0 : ~b0;
            mk1 &= ((ii.y >> bi) & 1) ? b1 : ~b1;
        }
        int rank0 = off0 + __popcll(mk0 & below);
        int rank1 = off1 + __popcll(mk1 & below);
        int c0 = rank0 < cap;
        int c1 = rank1 < cap;

        if (c0) msk[l * 128 + ii.x] = 1.f;
        if (c1) msk[l * 128 + 64 + ii.y] = 1.f;

        out_probs[2 * n]     = c0 ? pp.x : 0.f;
        out_probs[2 * n + 1] = c1 ? pp.y : 0.f;
        out_idx[2 * n]       = (float)ii.x;
        out_idx[2 * n + 1]   = (float)ii.y;
        out_rank[2 * n]      = (float)rank0;
        out_rank[2 * n + 1]  = (float)rank1;
    }
    __syncthreads();

    float* mrow = out_mask + (size_t)g * 8192;
    #pragma unroll
    for (int j = 0; j < 8; ++j) {
        size_t idx4 = (size_t)(j * 256 + t) * 4;
        *(float4*)(mrow + idx4) = *(float4*)&msk[idx4];
    }
}

extern "C" void kernel_launch(void* const* d_in, const int* in_sizes, int n_in,
                              void* d_out, int out_size, void* d_ws, size_t ws_size,
                              hipStream_t stream) {
    const float* x = (const float*)d_in[0];
    const float* w = (const float*)d_in[1];
    const int N = in_sizes[0] / C_DIM;    // 32768
    const int G = N / 64;                 // 512

    int cap = (int)floor(2.0 * 2.0 * (double)N / 64.0);
    cap += cap & 1;
    if (cap < 4) cap = 4;

    char* wsb = (char*)d_ws;
    _Float16* wfrag  = (_Float16*)wsb;    wsb += (size_t)131072 * 2;
    int2*   idx_ws   = (int2*)wsb;        wsb += (size_t)N * 8;
    float2* probs_ws = (float2*)wsb;      wsb += (size_t)N * 8;
    int*    hist     = (int*)wsb;         wsb += (size_t)G * 128 * 4;
    int*    offs     = (int*)wsb;         wsb += (size_t)G * 128 * 4;
    int*    tot      = (int*)wsb;

    float* out       = (float*)d_out;
    float* out_mask  = out;                          // N*2*64
    float* out_probs = out + (size_t)N * 128;        // N*2
    float* out_idx   = out_probs + (size_t)N * 2;    // N*2
    float* out_rank  = out_idx + (size_t)N * 2;      // N*2

    hipLaunchKernelGGL(wprep, dim3(64), dim3(256), 0, stream, w, wfrag,
                       hist, G * 128);
    hipLaunchKernelGGL(router_main, dim3(N / 32), dim3(512), 0, stream,
                       x, wfrag, idx_ws, probs_ws, hist);
    hipLaunchKernelGGL(scan_kernel, dim3(128), dim3(256), 0, stream,
                       hist, offs, tot, G);
    hipLaunchKernelGGL(rank_out, dim3(G), dim3(256), 0, stream,
                       idx_ws, probs_ws, offs, tot,
                       out_mask, out_probs, out_idx, out_rank, cap);
}

// Round 7
// 212.253 us; speedup vs baseline: 1.1294x; 1.1294x over previous
//
#include <hip/hip_runtime.h>
#include <math.h>

// Router: logits = x @ w^T (N=32768, C=1024, E=64), top-2 + softmax, stable
// k-major position-in-expert, capacity mask.
//
// R7 change vs R5: (1) per-block K-phase stagger — block b visits its 8
// K-chunks starting at (b&7), so the chip's instantaneous HBM address set
// spans 8x more channel phases (fixes lockstep channel camping);
// (2) prefetch-1 double-buffered LDS with raw s_waitcnt vmcnt(0)+s_barrier
// (only x-DMAs are outstanding at the drain point).

#define C_DIM 1024

typedef _Float16 f16x8 __attribute__((ext_vector_type(8)));
typedef float f32x16 __attribute__((ext_vector_type(16)));

#define DRAIN_BAR() asm volatile("s_waitcnt vmcnt(0)\ns_barrier" ::: "memory")

// wf frag id q = s*4 + eh*2 + split; elem = q*512 + lane*8
// content: n = eh*32 + (lane&31) (expert), k = s*16 + (lane>>5)*8 + j
__global__ __launch_bounds__(256) void wprep(const float* __restrict__ w,
                                             _Float16* __restrict__ wf) {
    int id = blockIdx.x * 256 + threadIdx.x;   // 16384 frags-of-8
    int lane = id & 63;
    int q = id >> 6;            // 0..255
    int split = q & 1;
    int eh = (q >> 1) & 1;
    int s = q >> 2;             // 0..63
    int n = eh * 32 + (lane & 31);
    int k = s * 16 + (lane >> 5) * 8;
    const float* src = w + (size_t)n * C_DIM + k;
    f16x8 v;
    #pragma unroll
    for (int j = 0; j < 8; ++j) {
        float xv = src[j];
        _Float16 h = (_Float16)xv;
        v[j] = (split == 0) ? h : (_Float16)((xv - (float)h) * 2048.0f);
    }
    *(f16x8*)(wf + (size_t)id * 8) = v;
}

__global__ __launch_bounds__(256, 2) void router_main(
    const float* __restrict__ x, const _Float16* __restrict__ wf,
    int2* __restrict__ idx_ws, float2* __restrict__ probs_ws,
    int* __restrict__ hist)
{
    // xs: 2 buffers x 64 rows x 128 floats = 64 KB. Within a buffer, 16B
    // chunk (m, c) lives at physical chunk (m, (c&16)|((c^(m&15))&15)):
    // ds_read_b128 conflict-free AND staging lane-contiguous (DMA constraint).
    __shared__ __align__(16) float xs[2 * 64 * 128];
    __shared__ int h2[128];

    const int tid  = threadIdx.x;
    const int lane = tid & 63;
    const int wv   = __builtin_amdgcn_readfirstlane(tid >> 6);
    const int th   = wv >> 1;      // token half
    const int eh   = wv & 1;       // expert half
    const int b    = blockIdx.x;
    const int m0   = b * 64;
    const int ph   = b & 7;        // K-phase stagger

    // staging map: 2048 16B chunks / 4 waves / 64 lanes = 8 instrs per thread
    uint32_t goff[8];
    const int p0 = wv * 512 + lane;
    #pragma unroll
    for (int i = 0; i < 8; ++i) {
        int p = p0 + i * 64;          // physical chunk index in buffer
        int m = p >> 5;               // row 0..63
        int rem = p & 31;             // physical chunk-in-row
        int c = (rem & 16) | ((rem ^ (m & 15)) & 15);   // logical chunk
        goff[i] = (uint32_t)(m0 + m) * C_DIM + c * 4;   // float offset (+k-chunk)
    }

    const int mm   = lane & 15;
    const int lh   = lane >> 5;
    const int mloc = th * 32 + (lane & 31);

    f32x16 ah, am;
    #pragma unroll
    for (int i = 0; i < 16; ++i) { ah[i] = 0.f; am[i] = 0.f; }

    const _Float16* wbase = wf + (size_t)eh * 1024 + (size_t)lane * 8;

    // prologue: chunk perm[0] -> buf 0
    #pragma unroll
    for (int i = 0; i < 8; ++i)
        __builtin_amdgcn_global_load_lds(
            (const __attribute__((address_space(1))) uint32_t*)(x + goff[i] + ph * 128),
            (__attribute__((address_space(3))) uint32_t*)(xs + (size_t)(wv * 512 + i * 64) * 4),
            16, 0, 0);

    #pragma unroll 1
    for (int it = 0; it < 8; ++it) {
        const int cur = it & 1;
        DRAIN_BAR();   // chunk perm[it] resident in buf[cur]; all waves synced
        if (it < 7) {
            const int cn = (ph + it + 1) & 7;
            float* dst = xs + (size_t)(cur ^ 1) * 8192;
            #pragma unroll
            for (int i = 0; i < 8; ++i)
                __builtin_amdgcn_global_load_lds(
                    (const __attribute__((address_space(1))) uint32_t*)(x + goff[i] + cn * 128),
                    (__attribute__((address_space(3))) uint32_t*)(dst + (size_t)(wv * 512 + i * 64) * 4),
                    16, 0, 0);
        }
        const int kbase = ((ph + it) & 7) * 8;
        const float* xb = xs + (size_t)cur * 8192;
        #pragma unroll
        for (int s8 = 0; s8 < 8; ++s8) {
            const int s  = kbase + s8;
            const int c0 = s8 * 4 + lh * 2;
            const int c1 = c0 + 1;
            const int pc0 = (c0 & 16) | ((c0 ^ mm) & 15);
            const int pc1 = (c1 & 16) | ((c1 ^ mm) & 15);
            float4 a0 = *(const float4*)&xb[(size_t)(mloc * 32 + pc0) * 4];
            float4 a1 = *(const float4*)&xb[(size_t)(mloc * 32 + pc1) * 4];
            float av[8] = {a0.x, a0.y, a0.z, a0.w, a1.x, a1.y, a1.z, a1.w};
            f16x8 xh, xm;
            #pragma unroll
            for (int j = 0; j < 8; ++j) {
                _Float16 hh = (_Float16)av[j];
                xh[j] = hh;
                xm[j] = (_Float16)((av[j] - (float)hh) * 2048.0f);
            }
            const _Float16* wp = wbase + (size_t)s * 2048;
            f16x8 bh = *(const f16x8*)(wp);
            f16x8 bm = *(const f16x8*)(wp + 512);
            ah = __builtin_amdgcn_mfma_f32_32x32x16_f16(xh, bh, ah, 0, 0, 0);
            am = __builtin_amdgcn_mfma_f32_32x32x16_f16(xh, bm, am, 0, 0, 0);
            am = __builtin_amdgcn_mfma_f32_32x32x16_f16(xm, bh, am, 0, 0, 0);
        }
        // next iteration's DRAIN_BAR syncs before buf[cur] is overwritten
    }
    __syncthreads();   // xs dead; alias buf0 as part[64][69]

    {
        const float inv = 1.0f / 2048.0f;
        const int col = lane & 31;
        #pragma unroll
        for (int reg = 0; reg < 16; ++reg) {
            int row = (reg & 3) + 8 * (reg >> 2) + 4 * lh;
            xs[(size_t)(th * 32 + row) * 69 + eh * 32 + col] = ah[reg] + am[reg] * inv;
        }
    }
    if (tid < 128) h2[tid] = 0;
    __syncthreads();

    if (tid < 64) {
        float m1 = -3.0e38f, m2 = -3.0e38f;
        int   i1 = 0, i2 = 0;
        const float* row = xs + (size_t)tid * 69;
        for (int e = 0; e < 64; ++e) {
            float v = row[e];
            if (v > m1)      { m2 = m1; i2 = i1; m1 = v; i1 = e; }
            else if (v > m2) { m2 = v;  i2 = e; }
        }
        float e2 = expf(m2 - m1);
        float p1 = 1.f / (1.f + e2);
        int n = m0 + tid;
        probs_ws[n] = make_float2(p1, e2 * p1);
        idx_ws[n]   = make_int2(i1, i2);
        atomicAdd(&h2[i1], 1);
        atomicAdd(&h2[64 + i2], 1);
    }
    __syncthreads();
    if (tid < 128) hist[(size_t)b * 128 + tid] = h2[tid];
}

// exclusive prefix over groups for each of the 128 (k,expert) columns
__global__ __launch_bounds__(256) void scan_kernel(const int* __restrict__ hist,
                                                   int* __restrict__ offs,
                                                   int* __restrict__ tot, int G) {
    int c = blockIdx.x;          // 0..127
    int t = threadIdx.x;
    int ipt = G / 256;
    int base = t * ipt;
    int sum = 0;
    for (int j = 0; j < ipt; ++j) sum += hist[(size_t)(base + j) * 128 + c];
    int lane = t & 63, wvi = t >> 6;
    int sc = sum;
    #pragma unroll
    for (int d = 1; d < 64; d <<= 1) {
        int o = __shfl_up(sc, d, 64);
        if (lane >= d) sc += o;
    }
    __shared__ int wtot[4];
    if (lane == 63) wtot[wvi] = sc;
    __syncthreads();
    int pre = 0;
    for (int w2 = 0; w2 < wvi; ++w2) pre += wtot[w2];
    int run = pre + sc - sum;
    for (int j = 0; j < ipt; ++j) {
        int v = hist[(size_t)(base + j) * 128 + c];
        offs[(size_t)(base + j) * 128 + c] = run;
        run += v;
    }
    if (t == 255) tot[c] = run;
}

__global__ __launch_bounds__(256) void rank_out(
    const int2* __restrict__ idx_ws, const float2* __restrict__ probs_ws,
    const int* __restrict__ offs, const int* __restrict__ tot,
    float* __restrict__ out_mask, float* __restrict__ out_probs,
    float* __restrict__ out_idx,  float* __restrict__ out_rank, int cap)
{
    __shared__ float msk[64 * 128];   // 32 KB
    const int g = blockIdx.x, t = threadIdx.x;

    #pragma unroll
    for (int j = 0; j < 8; ++j)
        *(float4*)&msk[(size_t)(j * 256 + t) * 4] = make_float4(0.f, 0.f, 0.f, 0.f);
    __syncthreads();

    if (t < 64) {
        const int l = t;
        const int n = g * 64 + l;
        int2   ii = idx_ws[n];
        float2 pp = probs_ws[n];
        int off0 = offs[g * 128 + ii.x];
        int off1 = offs[g * 128 + 64 + ii.y] + tot[ii.y];

        unsigned long long below = (1ull << l) - 1ull;
        unsigned long long mk0 = ~0ull, mk1 = ~0ull;
        #pragma unroll
        for (int bi = 0; bi < 6; ++bi) {
            unsigned long long b0 = __ballot((ii.x >> bi) & 1);
            unsigned long long b1 = __ballot((ii.y >> bi) & 1);
            mk0 &= ((ii.x >> bi) & 1) ? b0 : ~b0;
            mk1 &= ((ii.y >> bi) & 1) ? b1 : ~b1;
        }
        int rank0 = off0 + __popcll(mk0 & below);
        int rank1 = off1 + __popcll(mk1 & below);
        int c0 = rank0 < cap;
        int c1 = rank1 < cap;

        if (c0) msk[l * 128 + ii.x] = 1.f;
        if (c1) msk[l * 128 + 64 + ii.y] = 1.f;

        out_probs[2 * n]     = c0 ? pp.x : 0.f;
        out_probs[2 * n + 1] = c1 ? pp.y : 0.f;
        out_idx[2 * n]       = (float)ii.x;
        out_idx[2 * n + 1]   = (float)ii.y;
        out_rank[2 * n]      = (float)rank0;
        out_rank[2 * n + 1]  = (float)rank1;
    }
    __syncthreads();

    float* mrow = out_mask + (size_t)g * 8192;
    #pragma unroll
    for (int j = 0; j < 8; ++j) {
        size_t idx4 = (size_t)(j * 256 + t) * 4;
        *(float4*)(mrow + idx4) = *(float4*)&msk[idx4];
    }
}

extern "C" void kernel_launch(void* const* d_in, const int* in_sizes, int n_in,
                              void* d_out, int out_size, void* d_ws, size_t ws_size,
                              hipStream_t stream) {
    const float* x = (const float*)d_in[0];
    const float* w = (const float*)d_in[1];
    const int N = in_sizes[0] / C_DIM;    // 32768
    const int G = N / 64;                 // 512

    int cap = (int)floor(2.0 * 2.0 * (double)N / 64.0);
    cap += cap & 1;
    if (cap < 4) cap = 4;

    char* wsb = (char*)d_ws;
    _Float16* wfrag  = (_Float16*)wsb;    wsb += (size_t)131072 * 2;
    int2*   idx_ws   = (int2*)wsb;        wsb += (size_t)N * 8;
    float2* probs_ws = (float2*)wsb;      wsb += (size_t)N * 8;
    int*    hist     = (int*)wsb;         wsb += (size_t)G * 128 * 4;
    int*    offs     = (int*)wsb;         wsb += (size_t)G * 128 * 4;
    int*    tot      = (int*)wsb;

    float* out       = (float*)d_out;
    float* out_mask  = out;                          // N*2*64
    float* out_probs = out + (size_t)N * 128;        // N*2
    float* out_idx   = out_probs + (size_t)N * 2;    // N*2
    float* out_rank  = out_idx + (size_t)N * 2;      // N*2

    hipLaunchKernelGGL(wprep, dim3(64), dim3(256), 0, stream, w, wfrag);
    hipLaunchKernelGGL(router_main, dim3(G), dim3(256), 0, stream,
                       x, wfrag, idx_ws, probs_ws, hist);
    hipLaunchKernelGGL(scan_kernel, dim3(128), dim3(256), 0, stream,
                       hist, offs, tot, G);
    hipLaunchKernelGGL(rank_out, dim3(G), dim3(256), 0, stream,
                       idx_ws, probs_ws, offs, tot,
                       out_mask, out_probs, out_idx, out_rank, cap);
}